// Round 1
// baseline (2248.364 us; speedup 1.0000x reference)
//
#include <hip/hip_runtime.h>
#include <math.h>

#define NN 30000
#define NE 480000
#define NG 10

// ---------------------------------------------------------------------------
// Kernel 1: per-edge gains g[e][l], l=0..3
//   g = sum_j silu(b1[j] + emb . fc1[:,j]) * (fc2[j,:] . ea)
// ---------------------------------------------------------------------------
__global__ __launch_bounds__(256) void edge_g_kernel(
    const float* __restrict__ pos, const float* __restrict__ edge_attr,
    const int* __restrict__ esrc, const int* __restrict__ edst,
    const float* __restrict__ fc1, const float* __restrict__ b1,
    const float* __restrict__ fc2, float* __restrict__ g4)
{
    int e = blockIdx.x * 256 + threadIdx.x;
    if (e >= NE) return;
    int s = esrc[e], d = edst[e];
    float vx = pos[3*s+0] - pos[3*d+0];
    float vy = pos[3*s+1] - pos[3*d+1];
    float vz = pos[3*s+2] - pos[3*d+2];
    float r  = sqrtf(vx*vx + vy*vy + vz*vz);
    float inv = 1.0f / (r + 1e-12f);
    float ux = vx*inv, uy = vy*inv, uz = vz*inv;

    const float s3 = 1.73205081f, s5 = 2.23606798f, s15 = 3.87298335f;
    float ea[10];
    ea[0] = edge_attr[e];
    ea[1] = 1.0f;                 // sh0
    ea[2] = s3*ux; ea[3] = s3*uy; ea[4] = s3*uz;
    ea[5] = s15*ux*uz; ea[6] = s15*ux*uy;
    ea[7] = s5*(uy*uy - 0.5f*(ux*ux + uz*uz));
    ea[8] = s15*uy*uz;
    ea[9] = 0.5f*s15*(uz*uz - ux*ux);

    // soft_one_hot_linspace 'smooth_finite', cutoff=True, * sqrt(10)
    float emb[10];
    const float step = 4.0f/11.0f;
    const float C = 26.6692991f;  // 1.14136 * e^2 * sqrt(10)
    #pragma unroll
    for (int i = 0; i < 10; i++) {
        float dd = (r - step*(float)(i+1)) * (11.0f/4.0f);
        float d2 = dd*dd;
        emb[i] = (d2 < 1.0f) ? C * expf(-1.0f/(1.0f - d2)) : 0.0f;
    }

    #pragma unroll
    for (int l = 0; l < 4; l++) {
        const float* F1 = fc1 + l*1000;   // [10][100]
        const float* Bv = b1  + l*100;    // [100]
        const float* F2 = fc2 + l*1000;   // [100][10]
        float g = 0.0f;
        for (int j = 0; j < 100; j++) {
            float h = Bv[j];
            #pragma unroll
            for (int k = 0; k < 10; k++) h = fmaf(emb[k], F1[k*100 + j], h);
            h = h / (1.0f + expf(-h));    // silu
            float w = 0.0f;
            #pragma unroll
            for (int i = 0; i < 10; i++) w = fmaf(F2[j*10 + i], ea[i], w);
            g = fmaf(h, w, g);
        }
        g4[e*4 + l] = g;
    }
}

// ---------------------------------------------------------------------------
// CSR build: count, scan (single block), scatter
// ---------------------------------------------------------------------------
__global__ void count_deg_kernel(const int* __restrict__ edst, int* __restrict__ deg)
{
    int e = blockIdx.x * 256 + threadIdx.x;
    if (e < NE) atomicAdd(&deg[edst[e]], 1);
}

__global__ __launch_bounds__(1024) void scan_offsets_kernel(
    const int* __restrict__ deg, int* __restrict__ offs, int* __restrict__ cur)
{
    __shared__ int part[1024];
    int t = threadIdx.x;
    const int CH = (NN + 1023) / 1024;   // 30
    int base = t * CH;
    int s = 0;
    for (int i = 0; i < CH; i++) { int idx = base + i; if (idx < NN) s += deg[idx]; }
    part[t] = s;
    __syncthreads();
    for (int off = 1; off < 1024; off <<= 1) {
        int v = (t >= off) ? part[t - off] : 0;
        __syncthreads();
        part[t] += v;
        __syncthreads();
    }
    int run = (t == 0) ? 0 : part[t - 1];
    for (int i = 0; i < CH; i++) {
        int idx = base + i;
        if (idx < NN) { offs[idx] = run; cur[idx] = run; run += deg[idx]; }
    }
    if (t == 1023) offs[NN] = run;
}

__global__ void scatter_edges_kernel(const int* __restrict__ edst,
                                     int* __restrict__ cur, int* __restrict__ csr)
{
    int e = blockIdx.x * 256 + threadIdx.x;
    if (e < NE) {
        int slot = atomicAdd(&cur[edst[e]], 1);
        csr[slot] = e;
    }
}

// ---------------------------------------------------------------------------
// x0 = node_input * node_attr
// ---------------------------------------------------------------------------
__global__ void x0_kernel(const float* __restrict__ ni, const float* __restrict__ na,
                          float* __restrict__ x0)
{
    int i = blockIdx.x * 256 + threadIdx.x;
    if (i < NN * 8) x0[i] = ni[i] * na[i >> 3];
}

// ---------------------------------------------------------------------------
// Aggregation: agg[n][d] = 0.25 * sum_{e in csr(n)} g4[e][l] * xin[src(e)][d]
// thread per (n,d)
// ---------------------------------------------------------------------------
template <int D>
__global__ __launch_bounds__(256) void agg_kernel(
    const float* __restrict__ xin, const float* __restrict__ g4, int l,
    const int* __restrict__ offs, const int* __restrict__ csr,
    const int* __restrict__ esrc, float* __restrict__ agg)
{
    long idx = (long)blockIdx.x * 256 + threadIdx.x;
    if (idx >= (long)NN * D) return;
    int n = (int)(idx / D);
    int d = (int)(idx % D);
    int beg = offs[n], end = offs[n + 1];
    float acc = 0.0f;
    for (int p = beg; p < end; p++) {
        int e = csr[p];
        acc = fmaf(g4[e*4 + l], xin[(long)esrc[e]*D + d], acc);
    }
    agg[idx] = acc * 0.25f;   // 1/sqrt(16)
}

// ---------------------------------------------------------------------------
// GEMM C[M,N] = A[M,K] @ W[K,N], optional tanh. 32x32 tile, 2x2 micro-tile.
// ---------------------------------------------------------------------------
__global__ __launch_bounds__(256) void gemm_tanh_kernel(
    const float* __restrict__ A, const float* __restrict__ W,
    float* __restrict__ C, int M, int N, int K, int do_tanh)
{
    __shared__ float As[32][17];   // [row][k]
    __shared__ float Ws[16][33];   // [k][col]
    int tx = threadIdx.x, ty = threadIdx.y;       // 16 x 16
    int tid = ty * 16 + tx;
    int rowBase = blockIdx.y * 32;
    int colBase = blockIdx.x * 32;
    float acc00 = 0, acc01 = 0, acc10 = 0, acc11 = 0;

    for (int k0 = 0; k0 < K; k0 += 16) {
        // load A tile 32 x 16
        for (int i = tid; i < 32 * 16; i += 256) {
            int r = i >> 4, c = i & 15;
            int gr = rowBase + r, gc = k0 + c;
            As[r][c] = (gr < M && gc < K) ? A[(long)gr * K + gc] : 0.0f;
        }
        // load W tile 16 x 32
        for (int i = tid; i < 16 * 32; i += 256) {
            int r = i >> 5, c = i & 31;
            int gr = k0 + r, gc = colBase + c;
            Ws[r][c] = (gr < K && gc < N) ? W[(long)gr * N + gc] : 0.0f;
        }
        __syncthreads();
        #pragma unroll
        for (int kk = 0; kk < 16; kk++) {
            float a0 = As[ty][kk], a1 = As[ty + 16][kk];
            float w0 = Ws[kk][tx], w1 = Ws[kk][tx + 16];
            acc00 = fmaf(a0, w0, acc00);
            acc01 = fmaf(a0, w1, acc01);
            acc10 = fmaf(a1, w0, acc10);
            acc11 = fmaf(a1, w1, acc11);
        }
        __syncthreads();
    }
    int r0 = rowBase + ty, r1 = rowBase + ty + 16;
    int c0 = colBase + tx, c1 = colBase + tx + 16;
    if (do_tanh) {
        acc00 = tanhf(acc00); acc01 = tanhf(acc01);
        acc10 = tanhf(acc10); acc11 = tanhf(acc11);
    }
    if (r0 < M) {
        if (c0 < N) C[(long)r0 * N + c0] = acc00;
        if (c1 < N) C[(long)r0 * N + c1] = acc01;
    }
    if (r1 < M) {
        if (c0 < N) C[(long)r1 * N + c0] = acc10;
        if (c1 < N) C[(long)r1 * N + c1] = acc11;
    }
}

// ---------------------------------------------------------------------------
// Final: y = agg3 @ W3 [288,3]; pooled[g] += y / sqrt(3000)
// ---------------------------------------------------------------------------
__global__ __launch_bounds__(256) void final_kernel(
    const float* __restrict__ x, const float* __restrict__ W3,
    const int* __restrict__ batch, float* __restrict__ out)
{
    int n = blockIdx.x * 256 + threadIdx.x;
    if (n >= NN) return;
    float a0 = 0, a1 = 0, a2 = 0;
    const float* row = x + (long)n * 288;
    for (int k = 0; k < 288; k++) {
        float v = row[k];
        a0 = fmaf(v, W3[k*3 + 0], a0);
        a1 = fmaf(v, W3[k*3 + 1], a1);
        a2 = fmaf(v, W3[k*3 + 2], a2);
    }
    int g = batch[n];
    const float sc = 0.018257419f;   // 1/sqrt(3000)
    atomicAdd(&out[g*3 + 0], a0 * sc);
    atomicAdd(&out[g*3 + 1], a1 * sc);
    atomicAdd(&out[g*3 + 2], a2 * sc);
}

// ---------------------------------------------------------------------------
extern "C" void kernel_launch(void* const* d_in, const int* in_sizes, int n_in,
                              void* d_out, int out_size, void* d_ws, size_t ws_size,
                              hipStream_t stream)
{
    const float* pos        = (const float*)d_in[0];
    const float* node_input = (const float*)d_in[1];
    const float* node_attr  = (const float*)d_in[2];
    const float* edge_attr  = (const float*)d_in[3];
    const int*   edge_src   = (const int*)d_in[4];
    const int*   edge_dst   = (const int*)d_in[5];
    const int*   batch      = (const int*)d_in[6];
    const float* fc1        = (const float*)d_in[7];
    const float* b1         = (const float*)d_in[8];
    const float* fc2        = (const float*)d_in[9];
    const float* W0         = (const float*)d_in[10];
    const float* W1         = (const float*)d_in[11];
    const float* W2         = (const float*)d_in[12];
    const float* W3         = (const float*)d_in[13];
    float* out = (float*)d_out;

    // workspace layout
    float* g4   = (float*)d_ws;            // NE*4 floats
    int*   deg  = (int*)(g4 + (size_t)NE*4);
    int*   offs = deg + NN;                // NN+1
    int*   cur  = offs + NN + 1;
    int*   csr  = cur + NN;                // NE
    float* bufA = (float*)(csr + NE);      // NN*288
    float* bufB = bufA + (size_t)NN*288;
    float* bufC = bufB + (size_t)NN*288;

    hipMemsetAsync(deg, 0, NN * sizeof(int), stream);
    hipMemsetAsync(d_out, 0, NG * 3 * sizeof(float), stream);

    int eb = (NE + 255) / 256;
    edge_g_kernel<<<eb, 256, 0, stream>>>(pos, edge_attr, edge_src, edge_dst,
                                          fc1, b1, fc2, g4);
    count_deg_kernel<<<eb, 256, 0, stream>>>(edge_dst, deg);
    scan_offsets_kernel<<<1, 1024, 0, stream>>>(deg, offs, cur);
    scatter_edges_kernel<<<eb, 256, 0, stream>>>(edge_dst, cur, csr);

    x0_kernel<<<(NN*8 + 255)/256, 256, 0, stream>>>(node_input, node_attr, bufA);

    dim3 gblk(16, 16);
    dim3 ggrid(288/32, (NN + 31)/32);

    // layer 0: agg(x0)[N,8] -> x1 = tanh(agg @ W0) [N,288]
    agg_kernel<8><<<(NN*8 + 255)/256, 256, 0, stream>>>(bufA, g4, 0, offs, csr, edge_src, bufB);
    gemm_tanh_kernel<<<ggrid, gblk, 0, stream>>>(bufB, W0, bufC, NN, 288, 8, 1);

    // layer 1
    agg_kernel<288><<<((long)NN*288 + 255)/256, 256, 0, stream>>>(bufC, g4, 1, offs, csr, edge_src, bufA);
    gemm_tanh_kernel<<<ggrid, gblk, 0, stream>>>(bufA, W1, bufB, NN, 288, 288, 1);

    // layer 2
    agg_kernel<288><<<((long)NN*288 + 255)/256, 256, 0, stream>>>(bufB, g4, 2, offs, csr, edge_src, bufC);
    gemm_tanh_kernel<<<ggrid, gblk, 0, stream>>>(bufC, W2, bufA, NN, 288, 288, 1);

    // layer 3: agg then fused W3 + pool
    agg_kernel<288><<<((long)NN*288 + 255)/256, 256, 0, stream>>>(bufA, g4, 3, offs, csr, edge_src, bufB);
    final_kernel<<<(NN + 255)/256, 256, 0, stream>>>(bufB, W3, batch, out);
}

// Round 2
// 1620.850 us; speedup vs baseline: 1.3872x; 1.3872x over previous
//
#include <hip/hip_runtime.h>
#include <math.h>

#define NN 30000
#define NE 480000
#define NG 10

// ---------------------------------------------------------------------------
// Kernel 1: per-edge gains g[e][l], l=0..3
//   g = sum_j silu(b1[j] + emb . fc1[:,j]) * (fc2[j,:] . ea)
// ---------------------------------------------------------------------------
__global__ __launch_bounds__(256) void edge_g_kernel(
    const float* __restrict__ pos, const float* __restrict__ edge_attr,
    const int* __restrict__ esrc, const int* __restrict__ edst,
    const float* __restrict__ fc1, const float* __restrict__ b1,
    const float* __restrict__ fc2, float* __restrict__ g4)
{
    int e = blockIdx.x * 256 + threadIdx.x;
    if (e >= NE) return;
    int s = esrc[e], d = edst[e];
    float vx = pos[3*s+0] - pos[3*d+0];
    float vy = pos[3*s+1] - pos[3*d+1];
    float vz = pos[3*s+2] - pos[3*d+2];
    float r  = sqrtf(vx*vx + vy*vy + vz*vz);
    float inv = 1.0f / (r + 1e-12f);
    float ux = vx*inv, uy = vy*inv, uz = vz*inv;

    const float s3 = 1.73205081f, s5 = 2.23606798f, s15 = 3.87298335f;
    float ea[10];
    ea[0] = edge_attr[e];
    ea[1] = 1.0f;                 // sh0
    ea[2] = s3*ux; ea[3] = s3*uy; ea[4] = s3*uz;
    ea[5] = s15*ux*uz; ea[6] = s15*ux*uy;
    ea[7] = s5*(uy*uy - 0.5f*(ux*ux + uz*uz));
    ea[8] = s15*uy*uz;
    ea[9] = 0.5f*s15*(uz*uz - ux*ux);

    // soft_one_hot_linspace 'smooth_finite', cutoff=True, * sqrt(10)
    float emb[10];
    const float step = 4.0f/11.0f;
    const float C = 26.6692991f;  // 1.14136 * e^2 * sqrt(10)
    #pragma unroll
    for (int i = 0; i < 10; i++) {
        float dd = (r - step*(float)(i+1)) * (11.0f/4.0f);
        float d2 = dd*dd;
        emb[i] = (d2 < 1.0f) ? C * expf(-1.0f/(1.0f - d2)) : 0.0f;
    }

    #pragma unroll
    for (int l = 0; l < 4; l++) {
        const float* F1 = fc1 + l*1000;   // [10][100]
        const float* Bv = b1  + l*100;    // [100]
        const float* F2 = fc2 + l*1000;   // [100][10]
        float g = 0.0f;
        for (int j = 0; j < 100; j++) {
            float h = Bv[j];
            #pragma unroll
            for (int k = 0; k < 10; k++) h = fmaf(emb[k], F1[k*100 + j], h);
            h = h / (1.0f + expf(-h));    // silu
            float w = 0.0f;
            #pragma unroll
            for (int i = 0; i < 10; i++) w = fmaf(F2[j*10 + i], ea[i], w);
            g = fmaf(h, w, g);
        }
        g4[e*4 + l] = g;
    }
}

// ---------------------------------------------------------------------------
// CSR build: count, scan (single block), scatter
// ---------------------------------------------------------------------------
__global__ void count_deg_kernel(const int* __restrict__ edst, int* __restrict__ deg)
{
    int e = blockIdx.x * 256 + threadIdx.x;
    if (e < NE) atomicAdd(&deg[edst[e]], 1);
}

__global__ __launch_bounds__(1024) void scan_offsets_kernel(
    const int* __restrict__ deg, int* __restrict__ offs, int* __restrict__ cur)
{
    __shared__ int part[1024];
    int t = threadIdx.x;
    const int CH = (NN + 1023) / 1024;   // 30
    int base = t * CH;
    int s = 0;
    for (int i = 0; i < CH; i++) { int idx = base + i; if (idx < NN) s += deg[idx]; }
    part[t] = s;
    __syncthreads();
    for (int off = 1; off < 1024; off <<= 1) {
        int v = (t >= off) ? part[t - off] : 0;
        __syncthreads();
        part[t] += v;
        __syncthreads();
    }
    int run = (t == 0) ? 0 : part[t - 1];
    for (int i = 0; i < CH; i++) {
        int idx = base + i;
        if (idx < NN) { offs[idx] = run; cur[idx] = run; run += deg[idx]; }
    }
    if (t == 1023) offs[NN] = run;
}

__global__ void scatter_edges_kernel(const int* __restrict__ edst,
                                     int* __restrict__ cur, int* __restrict__ csr)
{
    int e = blockIdx.x * 256 + threadIdx.x;
    if (e < NE) {
        int slot = atomicAdd(&cur[edst[e]], 1);
        csr[slot] = e;
    }
}

// ---------------------------------------------------------------------------
// x0 = node_input * node_attr
// ---------------------------------------------------------------------------
__global__ void x0_kernel(const float* __restrict__ ni, const float* __restrict__ na,
                          float* __restrict__ x0)
{
    int i = blockIdx.x * 256 + threadIdx.x;
    if (i < NN * 8) x0[i] = ni[i] * na[i >> 3];
}

// ---------------------------------------------------------------------------
// Aggregation: agg[n][d] = 0.25 * sum_{e in csr(n)} g4[e][l] * xin[src(e)][d]
// thread per (n,d)
// ---------------------------------------------------------------------------
template <int D>
__global__ __launch_bounds__(256) void agg_kernel(
    const float* __restrict__ xin, const float* __restrict__ g4, int l,
    const int* __restrict__ offs, const int* __restrict__ csr,
    const int* __restrict__ esrc, float* __restrict__ agg)
{
    long idx = (long)blockIdx.x * 256 + threadIdx.x;
    if (idx >= (long)NN * D) return;
    int n = (int)(idx / D);
    int d = (int)(idx % D);
    int beg = offs[n], end = offs[n + 1];
    float acc = 0.0f;
    for (int p = beg; p < end; p++) {
        int e = csr[p];
        acc = fmaf(g4[e*4 + l], xin[(long)esrc[e]*D + d], acc);
    }
    agg[idx] = acc * 0.25f;   // 1/sqrt(16)
}

// ---------------------------------------------------------------------------
// GEMM C[M,N] = A[M,K] @ W[K,N], optional tanh. 32x32 tile, 2x2 micro-tile.
// ---------------------------------------------------------------------------
__global__ __launch_bounds__(256) void gemm_tanh_kernel(
    const float* __restrict__ A, const float* __restrict__ W,
    float* __restrict__ C, int M, int N, int K, int do_tanh)
{
    __shared__ float As[32][17];   // [row][k]
    __shared__ float Ws[16][33];   // [k][col]
    int tx = threadIdx.x, ty = threadIdx.y;       // 16 x 16
    int tid = ty * 16 + tx;
    int rowBase = blockIdx.y * 32;
    int colBase = blockIdx.x * 32;
    float acc00 = 0, acc01 = 0, acc10 = 0, acc11 = 0;

    for (int k0 = 0; k0 < K; k0 += 16) {
        // load A tile 32 x 16
        for (int i = tid; i < 32 * 16; i += 256) {
            int r = i >> 4, c = i & 15;
            int gr = rowBase + r, gc = k0 + c;
            As[r][c] = (gr < M && gc < K) ? A[(long)gr * K + gc] : 0.0f;
        }
        // load W tile 16 x 32
        for (int i = tid; i < 16 * 32; i += 256) {
            int r = i >> 5, c = i & 31;
            int gr = k0 + r, gc = colBase + c;
            Ws[r][c] = (gr < K && gc < N) ? W[(long)gr * N + gc] : 0.0f;
        }
        __syncthreads();
        #pragma unroll
        for (int kk = 0; kk < 16; kk++) {
            float a0 = As[ty][kk], a1 = As[ty + 16][kk];
            float w0 = Ws[kk][tx], w1 = Ws[kk][tx + 16];
            acc00 = fmaf(a0, w0, acc00);
            acc01 = fmaf(a0, w1, acc01);
            acc10 = fmaf(a1, w0, acc10);
            acc11 = fmaf(a1, w1, acc11);
        }
        __syncthreads();
    }
    int r0 = rowBase + ty, r1 = rowBase + ty + 16;
    int c0 = colBase + tx, c1 = colBase + tx + 16;
    if (do_tanh) {
        acc00 = tanhf(acc00); acc01 = tanhf(acc01);
        acc10 = tanhf(acc10); acc11 = tanhf(acc11);
    }
    if (r0 < M) {
        if (c0 < N) C[(long)r0 * N + c0] = acc00;
        if (c1 < N) C[(long)r0 * N + c1] = acc01;
    }
    if (r1 < M) {
        if (c0 < N) C[(long)r1 * N + c0] = acc10;
        if (c1 < N) C[(long)r1 * N + c1] = acc11;
    }
}

// ---------------------------------------------------------------------------
// Final: y = agg3 @ W3 [288,3]; pooled[g] += y / sqrt(3000)
// Block-local LDS reduction first; <=30 global atomics per block.
// ---------------------------------------------------------------------------
__global__ __launch_bounds__(256) void final_kernel(
    const float* __restrict__ x, const float* __restrict__ W3,
    const int* __restrict__ batch, float* __restrict__ out)
{
    __shared__ float part[NG * 3];
    int t = threadIdx.x;
    if (t < NG * 3) part[t] = 0.0f;
    __syncthreads();

    int n = blockIdx.x * 256 + t;
    if (n < NN) {
        float a0 = 0, a1 = 0, a2 = 0;
        const float* row = x + (long)n * 288;
        #pragma unroll 4
        for (int k = 0; k < 288; k += 4) {
            float4 v = *reinterpret_cast<const float4*>(row + k);
            a0 = fmaf(v.x, W3[(k+0)*3 + 0], a0);
            a1 = fmaf(v.x, W3[(k+0)*3 + 1], a1);
            a2 = fmaf(v.x, W3[(k+0)*3 + 2], a2);
            a0 = fmaf(v.y, W3[(k+1)*3 + 0], a0);
            a1 = fmaf(v.y, W3[(k+1)*3 + 1], a1);
            a2 = fmaf(v.y, W3[(k+1)*3 + 2], a2);
            a0 = fmaf(v.z, W3[(k+2)*3 + 0], a0);
            a1 = fmaf(v.z, W3[(k+2)*3 + 1], a1);
            a2 = fmaf(v.z, W3[(k+2)*3 + 2], a2);
            a0 = fmaf(v.w, W3[(k+3)*3 + 0], a0);
            a1 = fmaf(v.w, W3[(k+3)*3 + 1], a1);
            a2 = fmaf(v.w, W3[(k+3)*3 + 2], a2);
        }
        int g = batch[n];
        atomicAdd(&part[g*3 + 0], a0);
        atomicAdd(&part[g*3 + 1], a1);
        atomicAdd(&part[g*3 + 2], a2);
    }
    __syncthreads();
    if (t < NG * 3) {
        float v = part[t];
        const float sc = 0.018257419f;   // 1/sqrt(3000)
        if (v != 0.0f) atomicAdd(&out[t], v * sc);
    }
}

// ---------------------------------------------------------------------------
extern "C" void kernel_launch(void* const* d_in, const int* in_sizes, int n_in,
                              void* d_out, int out_size, void* d_ws, size_t ws_size,
                              hipStream_t stream)
{
    const float* pos        = (const float*)d_in[0];
    const float* node_input = (const float*)d_in[1];
    const float* node_attr  = (const float*)d_in[2];
    const float* edge_attr  = (const float*)d_in[3];
    const int*   edge_src   = (const int*)d_in[4];
    const int*   edge_dst   = (const int*)d_in[5];
    const int*   batch      = (const int*)d_in[6];
    const float* fc1        = (const float*)d_in[7];
    const float* b1         = (const float*)d_in[8];
    const float* fc2        = (const float*)d_in[9];
    const float* W0         = (const float*)d_in[10];
    const float* W1         = (const float*)d_in[11];
    const float* W2         = (const float*)d_in[12];
    const float* W3         = (const float*)d_in[13];
    float* out = (float*)d_out;

    // workspace layout
    float* g4   = (float*)d_ws;            // NE*4 floats
    int*   deg  = (int*)(g4 + (size_t)NE*4);
    int*   offs = deg + NN;                // NN+1
    int*   cur  = offs + NN + 1;
    int*   csr  = cur + NN;                // NE
    float* bufA = (float*)(csr + NE);      // NN*288
    float* bufB = bufA + (size_t)NN*288;
    float* bufC = bufB + (size_t)NN*288;

    hipMemsetAsync(deg, 0, NN * sizeof(int), stream);
    hipMemsetAsync(d_out, 0, NG * 3 * sizeof(float), stream);

    int eb = (NE + 255) / 256;
    edge_g_kernel<<<eb, 256, 0, stream>>>(pos, edge_attr, edge_src, edge_dst,
                                          fc1, b1, fc2, g4);
    count_deg_kernel<<<eb, 256, 0, stream>>>(edge_dst, deg);
    scan_offsets_kernel<<<1, 1024, 0, stream>>>(deg, offs, cur);
    scatter_edges_kernel<<<eb, 256, 0, stream>>>(edge_dst, cur, csr);

    x0_kernel<<<(NN*8 + 255)/256, 256, 0, stream>>>(node_input, node_attr, bufA);

    dim3 gblk(16, 16);
    dim3 ggrid(288/32, (NN + 31)/32);

    // layer 0: agg(x0)[N,8] -> x1 = tanh(agg @ W0) [N,288]
    agg_kernel<8><<<(NN*8 + 255)/256, 256, 0, stream>>>(bufA, g4, 0, offs, csr, edge_src, bufB);
    gemm_tanh_kernel<<<ggrid, gblk, 0, stream>>>(bufB, W0, bufC, NN, 288, 8, 1);

    // layer 1
    agg_kernel<288><<<((long)NN*288 + 255)/256, 256, 0, stream>>>(bufC, g4, 1, offs, csr, edge_src, bufA);
    gemm_tanh_kernel<<<ggrid, gblk, 0, stream>>>(bufA, W1, bufB, NN, 288, 288, 1);

    // layer 2
    agg_kernel<288><<<((long)NN*288 + 255)/256, 256, 0, stream>>>(bufB, g4, 2, offs, csr, edge_src, bufC);
    gemm_tanh_kernel<<<ggrid, gblk, 0, stream>>>(bufC, W2, bufA, NN, 288, 288, 1);

    // layer 3: agg then fused W3 + pool
    agg_kernel<288><<<((long)NN*288 + 255)/256, 256, 0, stream>>>(bufA, g4, 3, offs, csr, edge_src, bufB);
    final_kernel<<<(NN + 255)/256, 256, 0, stream>>>(bufB, W3, batch, out);
}

// Round 3
// 549.793 us; speedup vs baseline: 4.0895x; 2.9481x over previous
//
#include <hip/hip_runtime.h>
#include <math.h>

#define NN 30000
#define NE 480000
#define NG 10

typedef __attribute__((ext_vector_type(4))) float f32x4;
typedef __attribute__((ext_vector_type(8))) short short8;

__device__ __forceinline__ float bf2f(ushort u) {
    union { unsigned int i; float f; } x; x.i = ((unsigned int)u) << 16; return x.f;
}
__device__ __forceinline__ ushort f2bf(float f) {
    union { float f; unsigned int i; } x; x.f = f;
    unsigned int r = (x.i + 0x7FFFu + ((x.i >> 16) & 1u)) >> 16;
    return (ushort)r;
}
__device__ __forceinline__ unsigned int pack2(float a, float b) {
    return (unsigned int)f2bf(a) | ((unsigned int)f2bf(b) << 16);
}
struct F8 { float v0,v1,v2,v3,v4,v5,v6,v7; };
__device__ __forceinline__ F8 unpack8(uint4 v) {
    F8 r;
    r.v0 = bf2f((ushort)(v.x & 0xffffu)); r.v1 = bf2f((ushort)(v.x >> 16));
    r.v2 = bf2f((ushort)(v.y & 0xffffu)); r.v3 = bf2f((ushort)(v.y >> 16));
    r.v4 = bf2f((ushort)(v.z & 0xffffu)); r.v5 = bf2f((ushort)(v.z >> 16));
    r.v6 = bf2f((ushort)(v.w & 0xffffu)); r.v7 = bf2f((ushort)(v.w >> 16));
    return r;
}
__device__ __forceinline__ float fast_tanh(float x) {
    // tanh(x) = 1 - 2/(exp(2x)+1); stable at +-inf (inf -> 1, 0 -> -1 path ok)
    return 1.0f - 2.0f / (__expf(2.0f * x) + 1.0f);
}

// ---------------------------------------------------------------------------
// Weight prep: f1t[l][j][12] = fc1[l][k][j] (k<10, pad 0); f2p[l][j][12] = fc2[l][j][i]
// ---------------------------------------------------------------------------
__global__ void pad_mlp_kernel(const float* __restrict__ fc1, const float* __restrict__ fc2,
                               float* __restrict__ f1t, float* __restrict__ f2p)
{
    int id = blockIdx.x * 256 + threadIdx.x;
    if (id >= 4800) return;
    int l = id / 1200, r = id - l * 1200;
    int j = r / 12, k = r - j * 12;
    f1t[id] = (k < 10) ? fc1[l * 1000 + k * 100 + j] : 0.0f;
    f2p[id] = (k < 10) ? fc2[l * 1000 + j * 10 + k] : 0.0f;
}

// WT[n][k] = bf16(W[k][n])
__global__ void transw_kernel(const float* __restrict__ W, ushort* __restrict__ WT)
{
    int id = blockIdx.x * 256 + threadIdx.x;
    if (id >= 288 * 288) return;
    int n = id / 288, k = id - n * 288;
    WT[id] = f2bf(W[k * 288 + n]);
}

// ---------------------------------------------------------------------------
// Per-edge gains g4[e][l]; weights staged in LDS, 2 edges/thread
// ---------------------------------------------------------------------------
__global__ __launch_bounds__(256) void edge_g_kernel(
    const float* __restrict__ pos, const float* __restrict__ edge_attr,
    const int* __restrict__ esrc, const int* __restrict__ edst,
    const float* __restrict__ f1t, const float* __restrict__ f2p,
    const float* __restrict__ b1, float* __restrict__ g4)
{
    __shared__ float sF1[1200];
    __shared__ float sF2[1200];
    __shared__ float sB[100];
    int tid = threadIdx.x;
    int ebase = blockIdx.x * 512 + tid;

    float emb[2][10], ea[2][10];
    #pragma unroll
    for (int t = 0; t < 2; t++) {
        int e = ebase + t * 256;
        int ec = (e < NE) ? e : 0;
        int s = esrc[ec], d = edst[ec];
        float vx = pos[3*s+0] - pos[3*d+0];
        float vy = pos[3*s+1] - pos[3*d+1];
        float vz = pos[3*s+2] - pos[3*d+2];
        float r  = sqrtf(vx*vx + vy*vy + vz*vz);
        float inv = 1.0f / (r + 1e-12f);
        float ux = vx*inv, uy = vy*inv, uz = vz*inv;
        const float s3 = 1.73205081f, s5 = 2.23606798f, s15 = 3.87298335f;
        ea[t][0] = edge_attr[ec];
        ea[t][1] = 1.0f;
        ea[t][2] = s3*ux; ea[t][3] = s3*uy; ea[t][4] = s3*uz;
        ea[t][5] = s15*ux*uz; ea[t][6] = s15*ux*uy;
        ea[t][7] = s5*(uy*uy - 0.5f*(ux*ux + uz*uz));
        ea[t][8] = s15*uy*uz;
        ea[t][9] = 0.5f*s15*(uz*uz - ux*ux);
        const float C = 26.6692991f;  // 1.14136 * e^2 * sqrt(10)
        float rr = r * 2.75f;         // r / step, step = 4/11
        #pragma unroll
        for (int i = 0; i < 10; i++) {
            float dd = rr - (float)(i + 1);
            float d2 = dd * dd;
            emb[t][i] = (d2 < 1.0f) ? C * __expf(-1.0f / (1.0f - d2)) : 0.0f;
        }
    }

    float gout[2][4];
    #pragma unroll
    for (int l = 0; l < 4; l++) {
        __syncthreads();
        for (int i = tid; i < 1200; i += 256) {
            sF1[i] = f1t[l * 1200 + i];
            sF2[i] = f2p[l * 1200 + i];
        }
        if (tid < 100) sB[tid] = b1[l * 100 + tid];
        __syncthreads();
        float g[2] = {0.0f, 0.0f};
        for (int j = 0; j < 100; j++) {
            float4 A0 = *(const float4*)&sF1[j*12];
            float4 A1 = *(const float4*)&sF1[j*12+4];
            float2 A2 = *(const float2*)&sF1[j*12+8];
            float4 B0 = *(const float4*)&sF2[j*12];
            float4 B1 = *(const float4*)&sF2[j*12+4];
            float2 B2 = *(const float2*)&sF2[j*12+8];
            float bj = sB[j];
            #pragma unroll
            for (int t = 0; t < 2; t++) {
                float h = bj;
                h = fmaf(emb[t][0], A0.x, h); h = fmaf(emb[t][1], A0.y, h);
                h = fmaf(emb[t][2], A0.z, h); h = fmaf(emb[t][3], A0.w, h);
                h = fmaf(emb[t][4], A1.x, h); h = fmaf(emb[t][5], A1.y, h);
                h = fmaf(emb[t][6], A1.z, h); h = fmaf(emb[t][7], A1.w, h);
                h = fmaf(emb[t][8], A2.x, h); h = fmaf(emb[t][9], A2.y, h);
                h = h / (1.0f + __expf(-h));   // silu
                float w = 0.0f;
                w = fmaf(ea[t][0], B0.x, w); w = fmaf(ea[t][1], B0.y, w);
                w = fmaf(ea[t][2], B0.z, w); w = fmaf(ea[t][3], B0.w, w);
                w = fmaf(ea[t][4], B1.x, w); w = fmaf(ea[t][5], B1.y, w);
                w = fmaf(ea[t][6], B1.z, w); w = fmaf(ea[t][7], B1.w, w);
                w = fmaf(ea[t][8], B2.x, w); w = fmaf(ea[t][9], B2.y, w);
                g[t] = fmaf(h, w, g[t]);
            }
        }
        gout[0][l] = g[0]; gout[1][l] = g[1];
    }
    #pragma unroll
    for (int t = 0; t < 2; t++) {
        int e = ebase + t * 256;
        if (e < NE)
            *(float4*)&g4[e * 4] = make_float4(gout[t][0], gout[t][1], gout[t][2], gout[t][3]);
    }
}

// ---------------------------------------------------------------------------
// CSR build
// ---------------------------------------------------------------------------
__global__ void count_deg_kernel(const int* __restrict__ edst, int* __restrict__ deg)
{
    int e = blockIdx.x * 256 + threadIdx.x;
    if (e < NE) atomicAdd(&deg[edst[e]], 1);
}

__global__ __launch_bounds__(1024) void scan_offsets_kernel(
    const int* __restrict__ deg, int* __restrict__ offs, int* __restrict__ cur)
{
    __shared__ int part[1024];
    int t = threadIdx.x;
    const int CH = (NN + 1023) / 1024;
    int base = t * CH;
    int s = 0;
    for (int i = 0; i < CH; i++) { int idx = base + i; if (idx < NN) s += deg[idx]; }
    part[t] = s;
    __syncthreads();
    for (int off = 1; off < 1024; off <<= 1) {
        int v = (t >= off) ? part[t - off] : 0;
        __syncthreads();
        part[t] += v;
        __syncthreads();
    }
    int run = (t == 0) ? 0 : part[t - 1];
    for (int i = 0; i < CH; i++) {
        int idx = base + i;
        if (idx < NN) { offs[idx] = run; cur[idx] = run; run += deg[idx]; }
    }
    if (t == 1023) offs[NN] = run;
}

__global__ void scatter_edges_kernel(const int* __restrict__ edst, const int* __restrict__ esrc,
                                     int* __restrict__ cur, int* __restrict__ csr,
                                     int* __restrict__ csr_src)
{
    int e = blockIdx.x * 256 + threadIdx.x;
    if (e < NE) {
        int slot = atomicAdd(&cur[edst[e]], 1);
        csr[slot] = e;
        csr_src[slot] = esrc[e];
    }
}

// gcsr[l][p] = g4[csr[p]][l]
__global__ void permute_g_kernel(const float* __restrict__ g4, const int* __restrict__ csr,
                                 float* __restrict__ gcsr)
{
    int p = blockIdx.x * 256 + threadIdx.x;
    if (p >= NE) return;
    int e = csr[p];
    float4 g = *(const float4*)&g4[e * 4];
    gcsr[p] = g.x;
    gcsr[NE + p] = g.y;
    gcsr[2 * NE + p] = g.z;
    gcsr[3 * NE + p] = g.w;
}

// ---------------------------------------------------------------------------
// x0 = bf16(node_input * node_attr)   [NN][8]
// ---------------------------------------------------------------------------
__global__ void x0_kernel(const float* __restrict__ ni, const float* __restrict__ na,
                          ushort* __restrict__ x0)
{
    int n = blockIdx.x * 256 + threadIdx.x;
    if (n >= NN) return;
    float a = na[n];
    float4 v0 = *(const float4*)(ni + n * 8);
    float4 v1 = *(const float4*)(ni + n * 8 + 4);
    uint4 o;
    o.x = pack2(v0.x * a, v0.y * a);
    o.y = pack2(v0.z * a, v0.w * a);
    o.z = pack2(v1.x * a, v1.y * a);
    o.w = pack2(v1.z * a, v1.w * a);
    *(uint4*)(x0 + n * 8) = o;
}

// ---------------------------------------------------------------------------
// agg for D=8: thread per node
// ---------------------------------------------------------------------------
__global__ __launch_bounds__(256) void agg8_kernel(
    const ushort* __restrict__ x0, const float* __restrict__ gc,
    const int* __restrict__ offs, const int* __restrict__ csr_src,
    ushort* __restrict__ a0)
{
    int n = blockIdx.x * 256 + threadIdx.x;
    if (n >= NN) return;
    int beg = offs[n], end = offs[n + 1];
    float a[8] = {0,0,0,0,0,0,0,0};
    for (int p = beg; p < end; p++) {
        float g = gc[p];
        int s = csr_src[p];
        F8 f = unpack8(*(const uint4*)(x0 + (size_t)s * 8));
        a[0] = fmaf(g, f.v0, a[0]); a[1] = fmaf(g, f.v1, a[1]);
        a[2] = fmaf(g, f.v2, a[2]); a[3] = fmaf(g, f.v3, a[3]);
        a[4] = fmaf(g, f.v4, a[4]); a[5] = fmaf(g, f.v5, a[5]);
        a[6] = fmaf(g, f.v6, a[6]); a[7] = fmaf(g, f.v7, a[7]);
    }
    uint4 o;
    o.x = pack2(a[0]*0.25f, a[1]*0.25f);
    o.y = pack2(a[2]*0.25f, a[3]*0.25f);
    o.z = pack2(a[4]*0.25f, a[5]*0.25f);
    o.w = pack2(a[6]*0.25f, a[7]*0.25f);
    *(uint4*)(a0 + (size_t)n * 8) = o;
}

// ---------------------------------------------------------------------------
// agg for D=288: thread per (node, 8-chunk)
// ---------------------------------------------------------------------------
__global__ __launch_bounds__(256) void agg288_kernel(
    const ushort* __restrict__ xin, const float* __restrict__ gc,
    const int* __restrict__ offs, const int* __restrict__ csr_src,
    ushort* __restrict__ out)
{
    int idx = blockIdx.x * 256 + threadIdx.x;
    if (idx >= NN * 36) return;
    int n = idx / 36, c = idx - n * 36;
    int beg = offs[n], end = offs[n + 1];
    float a0=0,a1=0,a2=0,a3=0,a4=0,a5=0,a6=0,a7=0;
    const ushort* xb = xin + c * 8;
    for (int p = beg; p < end; p++) {
        float g = gc[p];
        int s = csr_src[p];
        F8 f = unpack8(*(const uint4*)(xb + (size_t)s * 288));
        a0 = fmaf(g, f.v0, a0); a1 = fmaf(g, f.v1, a1);
        a2 = fmaf(g, f.v2, a2); a3 = fmaf(g, f.v3, a3);
        a4 = fmaf(g, f.v4, a4); a5 = fmaf(g, f.v5, a5);
        a6 = fmaf(g, f.v6, a6); a7 = fmaf(g, f.v7, a7);
    }
    uint4 o;
    o.x = pack2(a0*0.25f, a1*0.25f);
    o.y = pack2(a2*0.25f, a3*0.25f);
    o.z = pack2(a4*0.25f, a5*0.25f);
    o.w = pack2(a6*0.25f, a7*0.25f);
    *(uint4*)(out + (size_t)idx * 8) = o;
}

// ---------------------------------------------------------------------------
// Layer-0 GEMM: x1 = tanh(a0[NN,8] @ W0[8,288]), bf16 in/out, fp32 W0
// ---------------------------------------------------------------------------
__global__ __launch_bounds__(256) void gemm0_kernel(
    const ushort* __restrict__ a0, const float* __restrict__ W0, ushort* __restrict__ x1)
{
    int idx = blockIdx.x * 256 + threadIdx.x;
    if (idx >= NN * 288) return;
    int n = idx / 288, c = idx - n * 288;
    F8 f = unpack8(*(const uint4*)(a0 + (size_t)n * 8));
    float h = 0.0f;
    h = fmaf(f.v0, W0[0*288+c], h); h = fmaf(f.v1, W0[1*288+c], h);
    h = fmaf(f.v2, W0[2*288+c], h); h = fmaf(f.v3, W0[3*288+c], h);
    h = fmaf(f.v4, W0[4*288+c], h); h = fmaf(f.v5, W0[5*288+c], h);
    h = fmaf(f.v6, W0[6*288+c], h); h = fmaf(f.v7, W0[7*288+c], h);
    x1[idx] = f2bf(fast_tanh(h));
}

// ---------------------------------------------------------------------------
// MFMA GEMM: C = tanh(A[M,288] @ W[288,288]) with BT[n][k] = W[k][n], all bf16.
// 96x96 tile, BK=32, 4 waves (2x2), 48x48 per wave (3x3 fragments).
// ---------------------------------------------------------------------------
__global__ __launch_bounds__(256) void mfma_gemm_kernel(
    const ushort* __restrict__ A, const ushort* __restrict__ BT,
    ushort* __restrict__ C, int M)
{
    __shared__ ushort As[96 * 40];   // row stride 40 ushorts = 80 B (conflict-free)
    __shared__ ushort Bs[96 * 40];
    int tid = threadIdx.x;
    int wave = tid >> 6, lane = tid & 63;
    int wr = wave >> 1, wc = wave & 1;
    int rb = blockIdx.y * 96, cb = blockIdx.x * 96;
    int kq = lane >> 4, rl = lane & 15;

    f32x4 acc[3][3];
    #pragma unroll
    for (int m = 0; m < 3; m++)
        #pragma unroll
        for (int n = 0; n < 3; n++)
            acc[m][n] = (f32x4){0.0f, 0.0f, 0.0f, 0.0f};

    for (int k0 = 0; k0 < 288; k0 += 32) {
        __syncthreads();
        for (int c = tid; c < 384; c += 256) {
            int r = c >> 2, ch = c & 3;
            int gr = rb + r;
            uint4 va = (gr < M) ? *(const uint4*)(A + (size_t)gr * 288 + k0 + ch * 8)
                                : make_uint4(0, 0, 0, 0);
            *(uint4*)&As[r * 40 + ch * 8] = va;
            uint4 vb = *(const uint4*)(BT + (size_t)(cb + r) * 288 + k0 + ch * 8);
            *(uint4*)&Bs[r * 40 + ch * 8] = vb;
        }
        __syncthreads();
        short8 a[3], b[3];
        #pragma unroll
        for (int m = 0; m < 3; m++)
            a[m] = *(const short8*)&As[(wr * 48 + m * 16 + rl) * 40 + kq * 8];
        #pragma unroll
        for (int n = 0; n < 3; n++)
            b[n] = *(const short8*)&Bs[(wc * 48 + n * 16 + rl) * 40 + kq * 8];
        #pragma unroll
        for (int m = 0; m < 3; m++)
            #pragma unroll
            for (int n = 0; n < 3; n++)
                acc[m][n] = __builtin_amdgcn_mfma_f32_16x16x32_bf16(a[m], b[n], acc[m][n], 0, 0, 0);
    }
    // epilogue: C/D layout col = lane&15, row = (lane>>4)*4 + q
    #pragma unroll
    for (int m = 0; m < 3; m++) {
        #pragma unroll
        for (int n = 0; n < 3; n++) {
            int col = cb + wc * 48 + n * 16 + rl;
            #pragma unroll
            for (int q = 0; q < 4; q++) {
                int row = rb + wr * 48 + m * 16 + kq * 4 + q;
                if (row < M)
                    C[(size_t)row * 288 + col] = f2bf(fast_tanh(acc[m][n][q]));
            }
        }
    }
}

// ---------------------------------------------------------------------------
// Final: y = agg3 @ W3 [288,3]; pooled[g] += y / sqrt(3000). W3 in LDS.
// ---------------------------------------------------------------------------
__global__ __launch_bounds__(256) void final_kernel(
    const ushort* __restrict__ x, const float* __restrict__ W3,
    const int* __restrict__ batch, float* __restrict__ out)
{
    __shared__ float sW[864];
    __shared__ float part[NG * 3];
    int t = threadIdx.x;
    for (int i = t; i < 864; i += 256) sW[i] = W3[i];
    if (t < NG * 3) part[t] = 0.0f;
    __syncthreads();

    int n = blockIdx.x * 256 + t;
    if (n < NN) {
        float a0 = 0, a1 = 0, a2 = 0;
        const ushort* row = x + (size_t)n * 288;
        for (int k = 0; k < 288; k += 8) {
            F8 f = unpack8(*(const uint4*)(row + k));
            a0 = fmaf(f.v0, sW[(k+0)*3+0], a0); a1 = fmaf(f.v0, sW[(k+0)*3+1], a1); a2 = fmaf(f.v0, sW[(k+0)*3+2], a2);
            a0 = fmaf(f.v1, sW[(k+1)*3+0], a0); a1 = fmaf(f.v1, sW[(k+1)*3+1], a1); a2 = fmaf(f.v1, sW[(k+1)*3+2], a2);
            a0 = fmaf(f.v2, sW[(k+2)*3+0], a0); a1 = fmaf(f.v2, sW[(k+2)*3+1], a1); a2 = fmaf(f.v2, sW[(k+2)*3+2], a2);
            a0 = fmaf(f.v3, sW[(k+3)*3+0], a0); a1 = fmaf(f.v3, sW[(k+3)*3+1], a1); a2 = fmaf(f.v3, sW[(k+3)*3+2], a2);
            a0 = fmaf(f.v4, sW[(k+4)*3+0], a0); a1 = fmaf(f.v4, sW[(k+4)*3+1], a1); a2 = fmaf(f.v4, sW[(k+4)*3+2], a2);
            a0 = fmaf(f.v5, sW[(k+5)*3+0], a0); a1 = fmaf(f.v5, sW[(k+5)*3+1], a1); a2 = fmaf(f.v5, sW[(k+5)*3+2], a2);
            a0 = fmaf(f.v6, sW[(k+6)*3+0], a0); a1 = fmaf(f.v6, sW[(k+6)*3+1], a1); a2 = fmaf(f.v6, sW[(k+6)*3+2], a2);
            a0 = fmaf(f.v7, sW[(k+7)*3+0], a0); a1 = fmaf(f.v7, sW[(k+7)*3+1], a1); a2 = fmaf(f.v7, sW[(k+7)*3+2], a2);
        }
        int g = batch[n];
        atomicAdd(&part[g*3 + 0], a0);
        atomicAdd(&part[g*3 + 1], a1);
        atomicAdd(&part[g*3 + 2], a2);
    }
    __syncthreads();
    if (t < NG * 3) {
        float v = part[t];
        if (v != 0.0f) atomicAdd(&out[t], v * 0.018257419f);
    }
}

// ---------------------------------------------------------------------------
extern "C" void kernel_launch(void* const* d_in, const int* in_sizes, int n_in,
                              void* d_out, int out_size, void* d_ws, size_t ws_size,
                              hipStream_t stream)
{
    const float* pos        = (const float*)d_in[0];
    const float* node_input = (const float*)d_in[1];
    const float* node_attr  = (const float*)d_in[2];
    const float* edge_attr  = (const float*)d_in[3];
    const int*   edge_src   = (const int*)d_in[4];
    const int*   edge_dst   = (const int*)d_in[5];
    const int*   batch      = (const int*)d_in[6];
    const float* fc1        = (const float*)d_in[7];
    const float* b1         = (const float*)d_in[8];
    const float* fc2        = (const float*)d_in[9];
    const float* W0         = (const float*)d_in[10];
    const float* W1         = (const float*)d_in[11];
    const float* W2         = (const float*)d_in[12];
    const float* W3         = (const float*)d_in[13];
    float* out = (float*)d_out;

    // workspace carve-up (256B aligned chunks)
    char* w = (char*)d_ws;
    auto alloc = [&](size_t bytes) { char* p = w; w += (bytes + 255) & ~(size_t)255; return p; };
    float*  g4      = (float*)alloc((size_t)NE * 4 * 4);
    float*  gcsr    = (float*)alloc((size_t)NE * 4 * 4);
    int*    deg     = (int*)alloc((size_t)NN * 4);
    int*    offs    = (int*)alloc((size_t)(NN + 1) * 4);
    int*    cur     = (int*)alloc((size_t)NN * 4);
    int*    csr     = (int*)alloc((size_t)NE * 4);
    int*    csr_src = (int*)alloc((size_t)NE * 4);
    float*  f1t     = (float*)alloc(4800 * 4);
    float*  f2p     = (float*)alloc(4800 * 4);
    ushort* w1t     = (ushort*)alloc(288 * 288 * 2);
    ushort* w2t     = (ushort*)alloc(288 * 288 * 2);
    ushort* x0      = (ushort*)alloc((size_t)NN * 8 * 2);
    ushort* a0      = (ushort*)alloc((size_t)NN * 8 * 2);
    ushort* P       = (ushort*)alloc((size_t)NN * 288 * 2);
    ushort* Q       = (ushort*)alloc((size_t)NN * 288 * 2);

    hipMemsetAsync(deg, 0, NN * sizeof(int), stream);
    hipMemsetAsync(d_out, 0, NG * 3 * sizeof(float), stream);

    pad_mlp_kernel<<<19, 256, 0, stream>>>(fc1, fc2, f1t, f2p);
    transw_kernel<<<324, 256, 0, stream>>>(W1, w1t);
    transw_kernel<<<324, 256, 0, stream>>>(W2, w2t);
    x0_kernel<<<(NN + 255) / 256, 256, 0, stream>>>(node_input, node_attr, x0);

    count_deg_kernel<<<1875, 256, 0, stream>>>(edge_dst, deg);
    scan_offsets_kernel<<<1, 1024, 0, stream>>>(deg, offs, cur);
    scatter_edges_kernel<<<1875, 256, 0, stream>>>(edge_dst, edge_src, cur, csr, csr_src);

    edge_g_kernel<<<938, 256, 0, stream>>>(pos, edge_attr, edge_src, edge_dst,
                                           f1t, f2p, b1, g4);
    permute_g_kernel<<<1875, 256, 0, stream>>>(g4, csr, gcsr);

    // layer 0
    agg8_kernel<<<(NN + 255) / 256, 256, 0, stream>>>(x0, gcsr, offs, csr_src, a0);
    gemm0_kernel<<<NN * 288 / 256, 256, 0, stream>>>(a0, W0, P);
    // layer 1
    agg288_kernel<<<(NN * 36 + 255) / 256, 256, 0, stream>>>(P, gcsr + NE, offs, csr_src, Q);
    mfma_gemm_kernel<<<dim3(3, 313), 256, 0, stream>>>(Q, w1t, P, NN);
    // layer 2
    agg288_kernel<<<(NN * 36 + 255) / 256, 256, 0, stream>>>(P, gcsr + 2 * NE, offs, csr_src, Q);
    mfma_gemm_kernel<<<dim3(3, 313), 256, 0, stream>>>(Q, w2t, P, NN);
    // layer 3
    agg288_kernel<<<(NN * 36 + 255) / 256, 256, 0, stream>>>(P, gcsr + 3 * NE, offs, csr_src, Q);
    final_kernel<<<(NN + 255) / 256, 256, 0, stream>>>(Q, W3, batch, out);
}